// Round 12
// baseline (743.201 us; speedup 1.0000x reference)
//
#include <hip/hip_runtime.h>

#define NL   4
#define NH   4
#define HD   64
#define CD   256
#define SQL  1024
#define BB   16

typedef _Float16 half8 __attribute__((ext_vector_type(8)));
typedef _Float16 half4 __attribute__((ext_vector_type(4)));
typedef _Float16 half2v __attribute__((ext_vector_type(2)));
typedef float    f32x4 __attribute__((ext_vector_type(4)));
typedef unsigned short u16x8 __attribute__((ext_vector_type(8)));

static __device__ __forceinline__ float bf2f(unsigned short u) {
    union { unsigned int i; float f; } v; v.i = ((unsigned int)u) << 16; return v.f;
}
static __device__ __forceinline__ unsigned short f2bf(float f) {
    union { float f; unsigned int i; } v; v.f = f;
    unsigned int u = v.i;
    return (unsigned short)((u + 0x7fffu + ((u >> 16) & 1u)) >> 16);
}

// inline dtype detect: 1 = inputs are packed bf16, 0 = f32. Uniform scalar loop.
static __device__ __forceinline__ int detect_flag(const void* win) {
    const unsigned int* w = (const unsigned int*)win;
    int cnt = 0;
#pragma unroll 1
    for (int i = 0; i < 64; i++) {
        unsigned int lo = w[i] & 0xFFFFu;
        int e = (int)((lo >> 7) & 0xFF);
        cnt += (e >= 96 && e <= 144) ? 1 : 0;
    }
    return cnt >= 48 ? 1 : 0;
}

// ---------- merged prep ----------
// x: (B,C,S)->(B,S,C) f16 row-major (gemm B-frags).
// kv: -> kaF / vtF in MFMA-A-FRAGMENT ORDER: per (layer*NH+h), per l-tile,
//     8 chunks of [64 lanes][8 halfs]; layer kernel reads coalesced dwordx4.
// w: elementwise cvt.
__global__ __launch_bounds__(256) void prep_all(const void* __restrict__ xin,
                                                const void* __restrict__ win,
                                                const void* __restrict__ kvin,
                                                _Float16* __restrict__ x16,
                                                _Float16* __restrict__ w16,
                                                _Float16* __restrict__ kaF,
                                                _Float16* __restrict__ vtF) {
    __shared__ __align__(16) _Float16 tile[64][72];
    const int bi = blockIdx.x;
    const int t = threadIdx.x;
    const int isbf = detect_flag(win);

    if (bi < 1024) {
        // ---- prep_x: (B,C,S) -> (B,S,C) f16 ----
        const int st = bi & 15, ct = (bi >> 4) & 3, b = bi >> 6;
        const int r = t >> 2, seg = t & 3;
        const size_t base = ((size_t)(b * CD + ct * 64 + r)) * SQL + st * 64 + seg * 16;
        float v[16];
        if (isbf) {
            const unsigned short* src = (const unsigned short*)xin + base;
            u16x8 u0 = *(const u16x8*)(src);
            u16x8 u1 = *(const u16x8*)(src + 8);
#pragma unroll
            for (int j = 0; j < 8; j++) { v[j] = bf2f(u0[j]); v[8 + j] = bf2f(u1[j]); }
        } else {
            const float* src = (const float*)xin + base;
#pragma unroll
            for (int c = 0; c < 4; c++) {
                f32x4 a = *(const f32x4*)(src + c * 4);
#pragma unroll
                for (int j = 0; j < 4; j++) v[c * 4 + j] = a[j];
            }
        }
#pragma unroll
        for (int j = 0; j < 16; j++) tile[r][seg * 16 + j] = (_Float16)v[j];
        __syncthreads();
        half8 o0, o1;
#pragma unroll
        for (int j = 0; j < 8; j++) { o0[j] = tile[seg * 16 + j][r]; o1[j] = tile[seg * 16 + 8 + j][r]; }
        _Float16* dt = x16 + ((size_t)(b * SQL + st * 64 + r)) * CD + ct * 64 + seg * 16;
        *(half8*)(dt) = o0;
        *(half8*)(dt + 8) = o1;
    } else if (bi < 1280) {
        // ---- prep_kv -> fragment-ordered kaF / vtF ----
        const int j2 = bi - 1024;
        const int lt = j2 & 15, ih = j2 >> 4;
        const int r = t >> 2, seg = t & 3;
        const size_t base = ((size_t)(ih * SQL + lt * 64 + r)) * HD + seg * 16;
        float v[16];
        if (isbf) {
            const unsigned short* src = (const unsigned short*)kvin + base;
            u16x8 u0 = *(const u16x8*)(src);
            u16x8 u1 = *(const u16x8*)(src + 8);
#pragma unroll
            for (int j = 0; j < 8; j++) { v[j] = bf2f(u0[j]); v[8 + j] = bf2f(u1[j]); }
        } else {
            const float* src = (const float*)kvin + base;
#pragma unroll
            for (int c = 0; c < 4; c++) {
                f32x4 a = *(const f32x4*)(src + c * 4);
#pragma unroll
                for (int j = 0; j < 4; j++) v[c * 4 + j] = a[j];
            }
        }
#pragma unroll
        for (int j = 0; j < 16; j++) tile[r][seg * 16 + j] = (_Float16)v[j];
        __syncthreads();
        const int l = t & 63, l16 = l & 15, q = l >> 4;
        _Float16* kaB = kaF + ((size_t)ih << 16);
        _Float16* vtB = vtF + ((size_t)ih << 16);
#pragma unroll
        for (int it = 0; it < 2; it++) {
            const int c = (t >> 6) + it * 4;       // 0..7
            const int kd = c >> 1, msp = c & 1;
            half8 ok, ov;
#pragma unroll
            for (int j = 0; j < 4; j++) {
                ok[j]     = tile[msp * 32 + l16][kd * 16 + q * 4 + j];
                ok[4 + j] = tile[msp * 32 + 16 + l16][kd * 16 + q * 4 + j];
                ov[j]     = tile[kd * 16 + q * 4 + j][msp * 32 + l16];
                ov[4 + j] = tile[kd * 16 + q * 4 + j][msp * 32 + 16 + l16];
            }
            *(half8*)(kaB + ((lt * 8 + c) << 9) + l * 8) = ok;
            *(half8*)(vtB + ((lt * 8 + c) << 9) + l * 8) = ov;
        }
    } else {
        // ---- prep_w: elementwise cvt ----
        const int i = (bi - 1280) * 256 + t;
        const size_t base = (size_t)i * 8;
        half8 h;
        if (isbf) {
            u16x8 u = *(const u16x8*)((const unsigned short*)win + base);
#pragma unroll
            for (int j = 0; j < 8; j++) h[j] = (_Float16)bf2f(u[j]);
        } else {
            const float* p = (const float*)win + base;
            f32x4 a0 = *(const f32x4*)(p);
            f32x4 a1 = *(const f32x4*)(p + 4);
#pragma unroll
            for (int j = 0; j < 4; j++) { h[j] = (_Float16)a0[j]; h[4 + j] = (_Float16)a1[j]; }
        }
        *(half8*)(w16 + base) = h;
    }
}

// ---------- fused layer: split-l, 4 waves/SIMD, zero-barrier main loop ----------
// Grid (16 s-tiles of 64, NH, BB) = 1024 blocks -> 4 blocks/CU. Waves 0,1 take
// l-tiles 0..7, waves 2,3 take 8..15 (same s as their pair partner). Softmax has
// no max-shift -> partials combine linearly: one LDS exchange + barrier at the
// END only. Main loop: pipelined register dataflow (K prefetch distance 2,
// V early-load), lsum via ones-A MFMA row-sum, exp2 w/ log2e folded into q.
__global__ __launch_bounds__(256, 4) void layer_fused(const _Float16* __restrict__ xg,
                                                      _Float16* __restrict__ xout,
                                                      const _Float16* __restrict__ w16,
                                                      const _Float16* __restrict__ kaF,
                                                      const _Float16* __restrict__ vtF,
                                                      const void* __restrict__ win,
                                                      void* __restrict__ outp,
                                                      int L) {
    __shared__ __align__(16) f32x4 comb[2][9][64];   // [pair][8 oacc + 1 lsum][lane]
    const int sb = blockIdx.x;     // 0..15 : s-tile of 64
    const int h  = blockIdx.y;
    const int b  = blockIdx.z;
    const int t  = threadIdx.x;
    const int wv = t >> 6, lane = t & 63, l16 = lane & 15, quad = lane >> 4;
    const int pair = wv & 1;             // which 32-s column group
    const int lhalf = wv >> 1;           // which l-half
    const int s0 = sb * 64 + pair * 32;  // wave's 32 s-columns

    // ---- gemm: q^T[d=64][s=32] for this head (duplicated across l-halves) ----
    f32x4 gacc[4][2];
#pragma unroll
    for (int md = 0; md < 4; md++)
#pragma unroll
        for (int nt = 0; nt < 2; nt++)
#pragma unroll
            for (int r = 0; r < 4; r++) gacc[md][nt][r] = 0.0f;
    const _Float16* wb = w16 + ((size_t)L << 16) + ((size_t)(h * 64) << 8);
#pragma unroll
    for (int kk = 0; kk < 8; kk++) {
        half8 bx[2];
#pragma unroll
        for (int nt = 0; nt < 2; nt++)
            bx[nt] = *(const half8*)(xg + ((size_t)((b << 10) + s0 + nt * 16 + l16) << 8) +
                                     kk * 32 + quad * 8);
#pragma unroll
        for (int md = 0; md < 4; md++) {
            half8 aw = *(const half8*)(wb + ((size_t)(md * 16 + l16) << 8) + kk * 32 + quad * 8);
            gacc[md][0] = __builtin_amdgcn_mfma_f32_16x16x32_f16(aw, bx[0], gacc[md][0], 0, 0, 0);
            gacc[md][1] = __builtin_amdgcn_mfma_f32_16x16x32_f16(aw, bx[1], gacc[md][1], 0, 0, 0);
        }
    }
    // q scale: 1/sqrt(64) * log2(e)
    half4 qh[4][2];
#pragma unroll
    for (int md = 0; md < 4; md++)
#pragma unroll
        for (int nt = 0; nt < 2; nt++)
#pragma unroll
            for (int r = 0; r < 4; r++)
                qh[md][nt][r] = (_Float16)(gacc[md][nt][r] * 0.180336880111120f);

    half4 ones4;
#pragma unroll
    for (int r = 0; r < 4; r++) ones4[r] = (_Float16)1.0f;

    const _Float16* kaB = kaF + ((size_t)(L * NH + h) << 16);
    const _Float16* vtB = vtF + ((size_t)(L * NH + h) << 16);
    const int lt0 = lhalf * 8;           // this wave's first l-tile

    f32x4 oacc[4][2];
    f32x4 osum[2];
#pragma unroll
    for (int md = 0; md < 4; md++)
#pragma unroll
        for (int nt = 0; nt < 2; nt++)
#pragma unroll
            for (int r = 0; r < 4; r++) oacc[md][nt][r] = 0.0f;
#pragma unroll
    for (int nt = 0; nt < 2; nt++)
#pragma unroll
        for (int r = 0; r < 4; r++) osum[nt][r] = 0.0f;

    // ---- pipelined attention over 8 l-tiles ----
    half8 kab[2][8];
    half8 vab[8];
    f32x4 sttC[4][2];

    auto loadK = [&](int lt, int buf) {
#pragma unroll
        for (int c = 0; c < 8; c++)
            kab[buf][c] = *(const half8*)(kaB + (((lt * 8 + c) << 9) + lane * 8));
    };
    auto loadV = [&](int lt) {
#pragma unroll
        for (int c = 0; c < 8; c++)
            vab[c] = *(const half8*)(vtB + (((lt * 8 + c) << 9) + lane * 8));
    };
    auto doQK = [&](int buf) {
#pragma unroll
        for (int ms = 0; ms < 4; ms++)
#pragma unroll
            for (int nt = 0; nt < 2; nt++)
#pragma unroll
                for (int r = 0; r < 4; r++) sttC[ms][nt][r] = 0.0f;
#pragma unroll
        for (int kd = 0; kd < 4; kd++)
#pragma unroll
            for (int msp = 0; msp < 2; msp++) {
                half8 kk8 = kab[buf][kd * 2 + msp];
                half4 lo = __builtin_shufflevector(kk8, kk8, 0, 1, 2, 3);
                half4 hi = __builtin_shufflevector(kk8, kk8, 4, 5, 6, 7);
#pragma unroll
                for (int nt = 0; nt < 2; nt++) {
                    sttC[msp * 2][nt] = __builtin_amdgcn_mfma_f32_16x16x16f16(
                        lo, qh[kd][nt], sttC[msp * 2][nt], 0, 0, 0);
                    sttC[msp * 2 + 1][nt] = __builtin_amdgcn_mfma_f32_16x16x16f16(
                        hi, qh[kd][nt], sttC[msp * 2 + 1][nt], 0, 0, 0);
                }
            }
    };

    loadK(lt0, 0);
    loadK(lt0 + 1, 1);
    doQK(0);

#pragma unroll 2
    for (int i = 0; i < 8; i++) {
        const int cb = i & 1, nb = cb ^ 1;
        if (i < 6) loadK(lt0 + i + 2, cb);
        loadV(lt0 + i);

        // exp2 of current scores -> P^T B-frags (VALU; independent of next QK)
        half4 pb[4][2];
#pragma unroll
        for (int ms = 0; ms < 4; ms++)
#pragma unroll
            for (int nt = 0; nt < 2; nt++) {
                float e0 = __builtin_amdgcn_exp2f(sttC[ms][nt][0]);
                float e1 = __builtin_amdgcn_exp2f(sttC[ms][nt][1]);
                float e2 = __builtin_amdgcn_exp2f(sttC[ms][nt][2]);
                float e3 = __builtin_amdgcn_exp2f(sttC[ms][nt][3]);
                half2v p01 = __builtin_bit_cast(half2v, __builtin_amdgcn_cvt_pkrtz(e0, e1));
                half2v p23 = __builtin_bit_cast(half2v, __builtin_amdgcn_cvt_pkrtz(e2, e3));
                pb[ms][nt] = __builtin_shufflevector(p01, p23, 0, 1, 2, 3);
            }

        // QK of NEXT tile (MFMA; co-schedules with the exp above)
        if (i < 7) doQK(nb);

        // PV of current tile + row-sum tile on the MFMA pipe
#pragma unroll
        for (int ks = 0; ks < 4; ks++) {
#pragma unroll
            for (int nt = 0; nt < 2; nt++)
                osum[nt] = __builtin_amdgcn_mfma_f32_16x16x16f16(
                    ones4, pb[ks][nt], osum[nt], 0, 0, 0);
#pragma unroll
            for (int mdp = 0; mdp < 2; mdp++) {
                half8 vv8 = vab[ks * 2 + mdp];
                half4 lo = __builtin_shufflevector(vv8, vv8, 0, 1, 2, 3);
                half4 hi = __builtin_shufflevector(vv8, vv8, 4, 5, 6, 7);
#pragma unroll
                for (int nt = 0; nt < 2; nt++) {
                    oacc[mdp * 2][nt] = __builtin_amdgcn_mfma_f32_16x16x16f16(
                        lo, pb[ks][nt], oacc[mdp * 2][nt], 0, 0, 0);
                    oacc[mdp * 2 + 1][nt] = __builtin_amdgcn_mfma_f32_16x16x16f16(
                        hi, pb[ks][nt], oacc[mdp * 2 + 1][nt], 0, 0, 0);
                }
            }
        }
    }

    // ---- combine l-halves: waves 2,3 publish partials; waves 0,1 reduce ----
    if (lhalf == 1) {
#pragma unroll
        for (int md = 0; md < 4; md++)
#pragma unroll
            for (int nt = 0; nt < 2; nt++)
                comb[pair][md * 2 + nt][lane] = oacc[md][nt];
        f32x4 ls;
        ls[0] = osum[0][0]; ls[1] = osum[1][0]; ls[2] = 0.0f; ls[3] = 0.0f;
        comb[pair][8][lane] = ls;
    }
    __syncthreads();
    if (lhalf == 0) {
#pragma unroll
        for (int md = 0; md < 4; md++)
#pragma unroll
            for (int nt = 0; nt < 2; nt++) {
                f32x4 o2 = comb[pair][md * 2 + nt][lane];
#pragma unroll
                for (int r = 0; r < 4; r++) oacc[md][nt][r] += o2[r];
            }
        f32x4 ls = comb[pair][8][lane];
        float inv[2];
        inv[0] = 1.0f / (osum[0][0] + ls[0]);
        inv[1] = 1.0f / (osum[1][0] + ls[1]);

        if (L < NL - 1) {
#pragma unroll
            for (int md = 0; md < 4; md++)
#pragma unroll
                for (int nt = 0; nt < 2; nt++) {
                    const int s = s0 + nt * 16 + l16;
                    half4 hv;
#pragma unroll
                    for (int r = 0; r < 4; r++) hv[r] = (_Float16)(oacc[md][nt][r] * inv[nt]);
                    *(half4*)(xout + (((size_t)((b << 10) + s)) << 8) + (h << 6) + md * 16 + quad * 4) = hv;
                }
        } else if (detect_flag(win)) {
#pragma unroll
            for (int md = 0; md < 4; md++)
#pragma unroll
                for (int nt = 0; nt < 2; nt++) {
                    const int s = s0 + nt * 16 + l16;
#pragma unroll
                    for (int r = 0; r < 4; r++) {
                        const int c = (h << 6) + md * 16 + quad * 4 + r;
                        ((unsigned short*)outp)[(((size_t)(b * CD + c)) << 10) + s] =
                            f2bf(oacc[md][nt][r] * inv[nt]);
                    }
                }
        } else {
#pragma unroll
            for (int md = 0; md < 4; md++)
#pragma unroll
                for (int nt = 0; nt < 2; nt++) {
                    const int s = s0 + nt * 16 + l16;
#pragma unroll
                    for (int r = 0; r < 4; r++) {
                        const int c = (h << 6) + md * 16 + quad * 4 + r;
                        ((float*)outp)[(((size_t)(b * CD + c)) << 10) + s] =
                            oacc[md][nt][r] * inv[nt];
                    }
                }
        }
    }
}

extern "C" void kernel_launch(void* const* d_in, const int* in_sizes, int n_in,
                              void* d_out, int out_size, void* d_ws, size_t ws_size,
                              hipStream_t stream) {
    const void* xin = d_in[0];
    // d_in[1] = length: used only for its shape (L=1024) — values irrelevant
    const void* win = d_in[2];
    const void* kvin = d_in[3];

    char* ws = (char*)d_ws;
    const size_t MB = 1u << 20;
    _Float16* xa  = (_Float16*)(ws);               // 8 MB  (B,S,C) f16
    _Float16* xb  = (_Float16*)(ws + 8 * MB);      // 8 MB  ping-pong
    _Float16* w16 = (_Float16*)(ws + 16 * MB);     // 0.5 MB
    _Float16* kaF = (_Float16*)(ws + 17 * MB);     // 2 MB  K fragment-order
    _Float16* vtF = (_Float16*)(ws + 19 * MB);     // 2 MB  V^T fragment-order

    prep_all<<<dim3(1024 + 256 + 128), 256, 0, stream>>>(xin, win, kvin, xa, w16, kaF, vtF);

    _Float16* cur = xa;
    _Float16* nxt = xb;
    for (int i = 0; i < NL; i++) {
        layer_fused<<<dim3(SQL / 64, NH, BB), 256, 0, stream>>>(cur, nxt, w16, kaF, vtF,
                                                                win, d_out, i);
        _Float16* tmp = cur; cur = nxt; nxt = tmp;
    }
}

// Round 13
// 275.376 us; speedup vs baseline: 2.6989x; 2.6989x over previous
//
#include <hip/hip_runtime.h>

#define NL   4
#define NH   4
#define HD   64
#define CD   256
#define SQL  1024
#define BB   16

typedef _Float16 half8 __attribute__((ext_vector_type(8)));
typedef _Float16 half4 __attribute__((ext_vector_type(4)));
typedef _Float16 half2v __attribute__((ext_vector_type(2)));
typedef float    f32x4 __attribute__((ext_vector_type(4)));
typedef unsigned short u16x8 __attribute__((ext_vector_type(8)));

static __device__ __forceinline__ float bf2f(unsigned short u) {
    union { unsigned int i; float f; } v; v.i = ((unsigned int)u) << 16; return v.f;
}
static __device__ __forceinline__ unsigned short f2bf(float f) {
    union { float f; unsigned int i; } v; v.f = f;
    unsigned int u = v.i;
    return (unsigned short)((u + 0x7fffu + ((u >> 16) & 1u)) >> 16);
}

// inline dtype detect: 1 = inputs are packed bf16, 0 = f32. Uniform scalar loop.
static __device__ __forceinline__ int detect_flag(const void* win) {
    const unsigned int* w = (const unsigned int*)win;
    int cnt = 0;
#pragma unroll 1
    for (int i = 0; i < 64; i++) {
        unsigned int lo = w[i] & 0xFFFFu;
        int e = (int)((lo >> 7) & 0xFF);
        cnt += (e >= 96 && e <= 144) ? 1 : 0;
    }
    return cnt >= 48 ? 1 : 0;
}

// ---------- merged prep ----------
// x: (B,C,S)->(B,S,C) f16 row-major (gemm B-frags).
// kv: -> kaF / vtF in MFMA-A-FRAGMENT ORDER: per (layer*NH+h), per l-tile,
//     8 chunks of [64 lanes][8 halfs]; layer kernel reads coalesced dwordx4.
// w: elementwise cvt.
__global__ __launch_bounds__(256) void prep_all(const void* __restrict__ xin,
                                                const void* __restrict__ win,
                                                const void* __restrict__ kvin,
                                                _Float16* __restrict__ x16,
                                                _Float16* __restrict__ w16,
                                                _Float16* __restrict__ kaF,
                                                _Float16* __restrict__ vtF) {
    __shared__ __align__(16) _Float16 tile[64][72];
    const int bi = blockIdx.x;
    const int t = threadIdx.x;
    const int isbf = detect_flag(win);

    if (bi < 1024) {
        // ---- prep_x: (B,C,S) -> (B,S,C) f16 ----
        const int st = bi & 15, ct = (bi >> 4) & 3, b = bi >> 6;
        const int r = t >> 2, seg = t & 3;
        const size_t base = ((size_t)(b * CD + ct * 64 + r)) * SQL + st * 64 + seg * 16;
        float v[16];
        if (isbf) {
            const unsigned short* src = (const unsigned short*)xin + base;
            u16x8 u0 = *(const u16x8*)(src);
            u16x8 u1 = *(const u16x8*)(src + 8);
#pragma unroll
            for (int j = 0; j < 8; j++) { v[j] = bf2f(u0[j]); v[8 + j] = bf2f(u1[j]); }
        } else {
            const float* src = (const float*)xin + base;
#pragma unroll
            for (int c = 0; c < 4; c++) {
                f32x4 a = *(const f32x4*)(src + c * 4);
#pragma unroll
                for (int j = 0; j < 4; j++) v[c * 4 + j] = a[j];
            }
        }
#pragma unroll
        for (int j = 0; j < 16; j++) tile[r][seg * 16 + j] = (_Float16)v[j];
        __syncthreads();
        half8 o0, o1;
#pragma unroll
        for (int j = 0; j < 8; j++) { o0[j] = tile[seg * 16 + j][r]; o1[j] = tile[seg * 16 + 8 + j][r]; }
        _Float16* dt = x16 + ((size_t)(b * SQL + st * 64 + r)) * CD + ct * 64 + seg * 16;
        *(half8*)(dt) = o0;
        *(half8*)(dt + 8) = o1;
    } else if (bi < 1280) {
        // ---- prep_kv -> fragment-ordered kaF / vtF ----
        const int j2 = bi - 1024;
        const int lt = j2 & 15, ih = j2 >> 4;
        const int r = t >> 2, seg = t & 3;
        const size_t base = ((size_t)(ih * SQL + lt * 64 + r)) * HD + seg * 16;
        float v[16];
        if (isbf) {
            const unsigned short* src = (const unsigned short*)kvin + base;
            u16x8 u0 = *(const u16x8*)(src);
            u16x8 u1 = *(const u16x8*)(src + 8);
#pragma unroll
            for (int j = 0; j < 8; j++) { v[j] = bf2f(u0[j]); v[8 + j] = bf2f(u1[j]); }
        } else {
            const float* src = (const float*)kvin + base;
#pragma unroll
            for (int c = 0; c < 4; c++) {
                f32x4 a = *(const f32x4*)(src + c * 4);
#pragma unroll
                for (int j = 0; j < 4; j++) v[c * 4 + j] = a[j];
            }
        }
#pragma unroll
        for (int j = 0; j < 16; j++) tile[r][seg * 16 + j] = (_Float16)v[j];
        __syncthreads();
        const int l = t & 63, l16 = l & 15, q = l >> 4;
        _Float16* kaB = kaF + ((size_t)ih << 16);
        _Float16* vtB = vtF + ((size_t)ih << 16);
#pragma unroll
        for (int it = 0; it < 2; it++) {
            const int c = (t >> 6) + it * 4;       // 0..7
            const int kd = c >> 1, msp = c & 1;
            half8 ok, ov;
#pragma unroll
            for (int j = 0; j < 4; j++) {
                ok[j]     = tile[msp * 32 + l16][kd * 16 + q * 4 + j];
                ok[4 + j] = tile[msp * 32 + 16 + l16][kd * 16 + q * 4 + j];
                ov[j]     = tile[kd * 16 + q * 4 + j][msp * 32 + l16];
                ov[4 + j] = tile[kd * 16 + q * 4 + j][msp * 32 + 16 + l16];
            }
            *(half8*)(kaB + ((lt * 8 + c) << 9) + l * 8) = ok;
            *(half8*)(vtB + ((lt * 8 + c) << 9) + l * 8) = ov;
        }
    } else {
        // ---- prep_w: elementwise cvt ----
        const int i = (bi - 1280) * 256 + t;
        const size_t base = (size_t)i * 8;
        half8 h;
        if (isbf) {
            u16x8 u = *(const u16x8*)((const unsigned short*)win + base);
#pragma unroll
            for (int j = 0; j < 8; j++) h[j] = (_Float16)bf2f(u[j]);
        } else {
            const float* p = (const float*)win + base;
            f32x4 a0 = *(const f32x4*)(p);
            f32x4 a1 = *(const f32x4*)(p + 4);
#pragma unroll
            for (int j = 0; j < 4; j++) { h[j] = (_Float16)a0[j]; h[4 + j] = (_Float16)a1[j]; }
        }
        *(half8*)(w16 + base) = h;
    }
}

// ---------- fused layer: split-l grid (4 blocks/CU), pipelined registers ----------
// Grid (16 s-tiles of 64, NH, BB) = 1024 blocks -> 4 blocks/CU. Waves 0,1 take
// l-tiles 0..7, waves 2,3 take 8..15 (same s as their pair partner). Softmax has
// no max-shift -> partials combine linearly: one LDS exchange + barrier at the
// END only. NOTE: launch_bounds min-waves stays 2 — asking for 4 caps VGPRs at
// 128 and forces catastrophic scratch spills (R12: 447 MB WRITE_SIZE, 190 us).
// Natural allocation is ~108 VGPR, which already lets 4 blocks/CU co-reside.
__global__ __launch_bounds__(256, 2) void layer_fused(const _Float16* __restrict__ xg,
                                                      _Float16* __restrict__ xout,
                                                      const _Float16* __restrict__ w16,
                                                      const _Float16* __restrict__ kaF,
                                                      const _Float16* __restrict__ vtF,
                                                      const void* __restrict__ win,
                                                      void* __restrict__ outp,
                                                      int L) {
    __shared__ __align__(16) f32x4 comb[2][9][64];   // [pair][8 oacc + 1 lsum][lane]
    const int sb = blockIdx.x;     // 0..15 : s-tile of 64
    const int h  = blockIdx.y;
    const int b  = blockIdx.z;
    const int t  = threadIdx.x;
    const int wv = t >> 6, lane = t & 63, l16 = lane & 15, quad = lane >> 4;
    const int pair = wv & 1;             // which 32-s column group
    const int lhalf = wv >> 1;           // which l-half
    const int s0 = sb * 64 + pair * 32;  // wave's 32 s-columns

    // ---- gemm: q^T[d=64][s=32] for this head (duplicated across l-halves) ----
    f32x4 gacc[4][2];
#pragma unroll
    for (int md = 0; md < 4; md++)
#pragma unroll
        for (int nt = 0; nt < 2; nt++)
#pragma unroll
            for (int r = 0; r < 4; r++) gacc[md][nt][r] = 0.0f;
    const _Float16* wb = w16 + ((size_t)L << 16) + ((size_t)(h * 64) << 8);
#pragma unroll
    for (int kk = 0; kk < 8; kk++) {
        half8 bx[2];
#pragma unroll
        for (int nt = 0; nt < 2; nt++)
            bx[nt] = *(const half8*)(xg + ((size_t)((b << 10) + s0 + nt * 16 + l16) << 8) +
                                     kk * 32 + quad * 8);
#pragma unroll
        for (int md = 0; md < 4; md++) {
            half8 aw = *(const half8*)(wb + ((size_t)(md * 16 + l16) << 8) + kk * 32 + quad * 8);
            gacc[md][0] = __builtin_amdgcn_mfma_f32_16x16x32_f16(aw, bx[0], gacc[md][0], 0, 0, 0);
            gacc[md][1] = __builtin_amdgcn_mfma_f32_16x16x32_f16(aw, bx[1], gacc[md][1], 0, 0, 0);
        }
    }
    // q scale: 1/sqrt(64) * log2(e)
    half4 qh[4][2];
#pragma unroll
    for (int md = 0; md < 4; md++)
#pragma unroll
        for (int nt = 0; nt < 2; nt++)
#pragma unroll
            for (int r = 0; r < 4; r++)
                qh[md][nt][r] = (_Float16)(gacc[md][nt][r] * 0.180336880111120f);

    half4 ones4;
#pragma unroll
    for (int r = 0; r < 4; r++) ones4[r] = (_Float16)1.0f;

    const _Float16* kaB = kaF + ((size_t)(L * NH + h) << 16);
    const _Float16* vtB = vtF + ((size_t)(L * NH + h) << 16);
    const int lt0 = lhalf * 8;           // this wave's first l-tile

    f32x4 oacc[4][2];
    f32x4 osum[2];
#pragma unroll
    for (int md = 0; md < 4; md++)
#pragma unroll
        for (int nt = 0; nt < 2; nt++)
#pragma unroll
            for (int r = 0; r < 4; r++) oacc[md][nt][r] = 0.0f;
#pragma unroll
    for (int nt = 0; nt < 2; nt++)
#pragma unroll
        for (int r = 0; r < 4; r++) osum[nt][r] = 0.0f;

    // ---- pipelined attention over 8 l-tiles ----
    half8 kab[2][8];
    half8 vab[8];
    f32x4 sttC[4][2];

    auto loadK = [&](int lt, int buf) {
#pragma unroll
        for (int c = 0; c < 8; c++)
            kab[buf][c] = *(const half8*)(kaB + (((lt * 8 + c) << 9) + lane * 8));
    };
    auto loadV = [&](int lt) {
#pragma unroll
        for (int c = 0; c < 8; c++)
            vab[c] = *(const half8*)(vtB + (((lt * 8 + c) << 9) + lane * 8));
    };
    auto doQK = [&](int buf) {
#pragma unroll
        for (int ms = 0; ms < 4; ms++)
#pragma unroll
            for (int nt = 0; nt < 2; nt++)
#pragma unroll
                for (int r = 0; r < 4; r++) sttC[ms][nt][r] = 0.0f;
#pragma unroll
        for (int kd = 0; kd < 4; kd++)
#pragma unroll
            for (int msp = 0; msp < 2; msp++) {
                half8 kk8 = kab[buf][kd * 2 + msp];
                half4 lo = __builtin_shufflevector(kk8, kk8, 0, 1, 2, 3);
                half4 hi = __builtin_shufflevector(kk8, kk8, 4, 5, 6, 7);
#pragma unroll
                for (int nt = 0; nt < 2; nt++) {
                    sttC[msp * 2][nt] = __builtin_amdgcn_mfma_f32_16x16x16f16(
                        lo, qh[kd][nt], sttC[msp * 2][nt], 0, 0, 0);
                    sttC[msp * 2 + 1][nt] = __builtin_amdgcn_mfma_f32_16x16x16f16(
                        hi, qh[kd][nt], sttC[msp * 2 + 1][nt], 0, 0, 0);
                }
            }
    };

    loadK(lt0, 0);
    loadK(lt0 + 1, 1);
    doQK(0);

#pragma unroll 2
    for (int i = 0; i < 8; i++) {
        const int cb = i & 1, nb = cb ^ 1;
        if (i < 6) loadK(lt0 + i + 2, cb);
        loadV(lt0 + i);

        // exp2 of current scores -> P^T B-frags (VALU; independent of next QK)
        half4 pb[4][2];
#pragma unroll
        for (int ms = 0; ms < 4; ms++)
#pragma unroll
            for (int nt = 0; nt < 2; nt++) {
                float e0 = __builtin_amdgcn_exp2f(sttC[ms][nt][0]);
                float e1 = __builtin_amdgcn_exp2f(sttC[ms][nt][1]);
                float e2 = __builtin_amdgcn_exp2f(sttC[ms][nt][2]);
                float e3 = __builtin_amdgcn_exp2f(sttC[ms][nt][3]);
                half2v p01 = __builtin_bit_cast(half2v, __builtin_amdgcn_cvt_pkrtz(e0, e1));
                half2v p23 = __builtin_bit_cast(half2v, __builtin_amdgcn_cvt_pkrtz(e2, e3));
                pb[ms][nt] = __builtin_shufflevector(p01, p23, 0, 1, 2, 3);
            }

        // QK of NEXT tile (MFMA; co-schedules with the exp above)
        if (i < 7) doQK(nb);

        // PV of current tile + row-sum tile on the MFMA pipe
#pragma unroll
        for (int ks = 0; ks < 4; ks++) {
#pragma unroll
            for (int nt = 0; nt < 2; nt++)
                osum[nt] = __builtin_amdgcn_mfma_f32_16x16x16f16(
                    ones4, pb[ks][nt], osum[nt], 0, 0, 0);
#pragma unroll
            for (int mdp = 0; mdp < 2; mdp++) {
                half8 vv8 = vab[ks * 2 + mdp];
                half4 lo = __builtin_shufflevector(vv8, vv8, 0, 1, 2, 3);
                half4 hi = __builtin_shufflevector(vv8, vv8, 4, 5, 6, 7);
#pragma unroll
                for (int nt = 0; nt < 2; nt++) {
                    oacc[mdp * 2][nt] = __builtin_amdgcn_mfma_f32_16x16x16f16(
                        lo, pb[ks][nt], oacc[mdp * 2][nt], 0, 0, 0);
                    oacc[mdp * 2 + 1][nt] = __builtin_amdgcn_mfma_f32_16x16x16f16(
                        hi, pb[ks][nt], oacc[mdp * 2 + 1][nt], 0, 0, 0);
                }
            }
        }
    }

    // ---- combine l-halves: waves 2,3 publish partials; waves 0,1 reduce ----
    if (lhalf == 1) {
#pragma unroll
        for (int md = 0; md < 4; md++)
#pragma unroll
            for (int nt = 0; nt < 2; nt++)
                comb[pair][md * 2 + nt][lane] = oacc[md][nt];
        f32x4 ls;
        ls[0] = osum[0][0]; ls[1] = osum[1][0]; ls[2] = 0.0f; ls[3] = 0.0f;
        comb[pair][8][lane] = ls;
    }
    __syncthreads();
    if (lhalf == 0) {
#pragma unroll
        for (int md = 0; md < 4; md++)
#pragma unroll
            for (int nt = 0; nt < 2; nt++) {
                f32x4 o2 = comb[pair][md * 2 + nt][lane];
#pragma unroll
                for (int r = 0; r < 4; r++) oacc[md][nt][r] += o2[r];
            }
        f32x4 ls = comb[pair][8][lane];
        float inv[2];
        inv[0] = 1.0f / (osum[0][0] + ls[0]);
        inv[1] = 1.0f / (osum[1][0] + ls[1]);

        if (L < NL - 1) {
#pragma unroll
            for (int md = 0; md < 4; md++)
#pragma unroll
                for (int nt = 0; nt < 2; nt++) {
                    const int s = s0 + nt * 16 + l16;
                    half4 hv;
#pragma unroll
                    for (int r = 0; r < 4; r++) hv[r] = (_Float16)(oacc[md][nt][r] * inv[nt]);
                    *(half4*)(xout + (((size_t)((b << 10) + s)) << 8) + (h << 6) + md * 16 + quad * 4) = hv;
                }
        } else if (detect_flag(win)) {
#pragma unroll
            for (int md = 0; md < 4; md++)
#pragma unroll
                for (int nt = 0; nt < 2; nt++) {
                    const int s = s0 + nt * 16 + l16;
#pragma unroll
                    for (int r = 0; r < 4; r++) {
                        const int c = (h << 6) + md * 16 + quad * 4 + r;
                        ((unsigned short*)outp)[(((size_t)(b * CD + c)) << 10) + s] =
                            f2bf(oacc[md][nt][r] * inv[nt]);
                    }
                }
        } else {
#pragma unroll
            for (int md = 0; md < 4; md++)
#pragma unroll
                for (int nt = 0; nt < 2; nt++) {
                    const int s = s0 + nt * 16 + l16;
#pragma unroll
                    for (int r = 0; r < 4; r++) {
                        const int c = (h << 6) + md * 16 + quad * 4 + r;
                        ((float*)outp)[(((size_t)(b * CD + c)) << 10) + s] =
                            oacc[md][nt][r] * inv[nt];
                    }
                }
        }
    }
}

extern "C" void kernel_launch(void* const* d_in, const int* in_sizes, int n_in,
                              void* d_out, int out_size, void* d_ws, size_t ws_size,
                              hipStream_t stream) {
    const void* xin = d_in[0];
    // d_in[1] = length: used only for its shape (L=1024) — values irrelevant
    const void* win = d_in[2];
    const void* kvin = d_in[3];

    char* ws = (char*)d_ws;
    const size_t MB = 1u << 20;
    _Float16* xa  = (_Float16*)(ws);               // 8 MB  (B,S,C) f16
    _Float16* xb  = (_Float16*)(ws + 8 * MB);      // 8 MB  ping-pong
    _Float16* w16 = (_Float16*)(ws + 16 * MB);     // 0.5 MB
    _Float16* kaF = (_Float16*)(ws + 17 * MB);     // 2 MB  K fragment-order
    _Float16* vtF = (_Float16*)(ws + 19 * MB);     // 2 MB  V^T fragment-order

    prep_all<<<dim3(1024 + 256 + 128), 256, 0, stream>>>(xin, win, kvin, xa, w16, kaF, vtF);

    _Float16* cur = xa;
    _Float16* nxt = xb;
    for (int i = 0; i < NL; i++) {
        layer_fused<<<dim3(SQL / 64, NH, BB), 256, 0, stream>>>(cur, nxt, w16, kaF, vtF,
                                                                win, d_out, i);
        _Float16* tmp = cur; cur = nxt; nxt = tmp;
    }
}

// Round 14
// 224.939 us; speedup vs baseline: 3.3040x; 1.2242x over previous
//
#include <hip/hip_runtime.h>

#define NL   4
#define NH   4
#define HD   64
#define CD   256
#define SQL  1024
#define BB   16

typedef _Float16 half8 __attribute__((ext_vector_type(8)));
typedef _Float16 half4 __attribute__((ext_vector_type(4)));
typedef _Float16 half2v __attribute__((ext_vector_type(2)));
typedef float    f32x4 __attribute__((ext_vector_type(4)));
typedef unsigned short u16x8 __attribute__((ext_vector_type(8)));

static __device__ __forceinline__ float bf2f(unsigned short u) {
    union { unsigned int i; float f; } v; v.i = ((unsigned int)u) << 16; return v.f;
}
static __device__ __forceinline__ unsigned short f2bf(float f) {
    union { float f; unsigned int i; } v; v.f = f;
    unsigned int u = v.i;
    return (unsigned short)((u + 0x7fffu + ((u >> 16) & 1u)) >> 16);
}

// inline dtype detect: 1 = inputs are packed bf16, 0 = f32. Uniform scalar loop.
static __device__ __forceinline__ int detect_flag(const void* win) {
    const unsigned int* w = (const unsigned int*)win;
    int cnt = 0;
#pragma unroll 1
    for (int i = 0; i < 64; i++) {
        unsigned int lo = w[i] & 0xFFFFu;
        int e = (int)((lo >> 7) & 0xFF);
        cnt += (e >= 96 && e <= 144) ? 1 : 0;
    }
    return cnt >= 48 ? 1 : 0;
}

// ---------- merged prep ----------
// x: (B,C,S)->(B,S,C) f16 row-major (gemm B-frags).
// kv: -> kaF / vtF in MFMA-A-FRAGMENT ORDER: per (layer*NH+h), per l-tile,
//     8 chunks of [64 lanes][8 halfs]; glds-compatible (uniform base + lane*16B).
// w: elementwise cvt.
__global__ __launch_bounds__(256) void prep_all(const void* __restrict__ xin,
                                                const void* __restrict__ win,
                                                const void* __restrict__ kvin,
                                                _Float16* __restrict__ x16,
                                                _Float16* __restrict__ w16,
                                                _Float16* __restrict__ kaF,
                                                _Float16* __restrict__ vtF) {
    __shared__ __align__(16) _Float16 tile[64][72];
    const int bi = blockIdx.x;
    const int t = threadIdx.x;
    const int isbf = detect_flag(win);

    if (bi < 1024) {
        // ---- prep_x: (B,C,S) -> (B,S,C) f16 ----
        const int st = bi & 15, ct = (bi >> 4) & 3, b = bi >> 6;
        const int r = t >> 2, seg = t & 3;
        const size_t base = ((size_t)(b * CD + ct * 64 + r)) * SQL + st * 64 + seg * 16;
        float v[16];
        if (isbf) {
            const unsigned short* src = (const unsigned short*)xin + base;
            u16x8 u0 = *(const u16x8*)(src);
            u16x8 u1 = *(const u16x8*)(src + 8);
#pragma unroll
            for (int j = 0; j < 8; j++) { v[j] = bf2f(u0[j]); v[8 + j] = bf2f(u1[j]); }
        } else {
            const float* src = (const float*)xin + base;
#pragma unroll
            for (int c = 0; c < 4; c++) {
                f32x4 a = *(const f32x4*)(src + c * 4);
#pragma unroll
                for (int j = 0; j < 4; j++) v[c * 4 + j] = a[j];
            }
        }
#pragma unroll
        for (int j = 0; j < 16; j++) tile[r][seg * 16 + j] = (_Float16)v[j];
        __syncthreads();
        half8 o0, o1;
#pragma unroll
        for (int j = 0; j < 8; j++) { o0[j] = tile[seg * 16 + j][r]; o1[j] = tile[seg * 16 + 8 + j][r]; }
        _Float16* dt = x16 + ((size_t)(b * SQL + st * 64 + r)) * CD + ct * 64 + seg * 16;
        *(half8*)(dt) = o0;
        *(half8*)(dt + 8) = o1;
    } else if (bi < 1280) {
        // ---- prep_kv -> fragment-ordered kaF / vtF ----
        const int j2 = bi - 1024;
        const int lt = j2 & 15, ih = j2 >> 4;
        const int r = t >> 2, seg = t & 3;
        const size_t base = ((size_t)(ih * SQL + lt * 64 + r)) * HD + seg * 16;
        float v[16];
        if (isbf) {
            const unsigned short* src = (const unsigned short*)kvin + base;
            u16x8 u0 = *(const u16x8*)(src);
            u16x8 u1 = *(const u16x8*)(src + 8);
#pragma unroll
            for (int j = 0; j < 8; j++) { v[j] = bf2f(u0[j]); v[8 + j] = bf2f(u1[j]); }
        } else {
            const float* src = (const float*)kvin + base;
#pragma unroll
            for (int c = 0; c < 4; c++) {
                f32x4 a = *(const f32x4*)(src + c * 4);
#pragma unroll
                for (int j = 0; j < 4; j++) v[c * 4 + j] = a[j];
            }
        }
#pragma unroll
        for (int j = 0; j < 16; j++) tile[r][seg * 16 + j] = (_Float16)v[j];
        __syncthreads();
        const int l = t & 63, l16 = l & 15, q = l >> 4;
        _Float16* kaB = kaF + ((size_t)ih << 16);
        _Float16* vtB = vtF + ((size_t)ih << 16);
#pragma unroll
        for (int it = 0; it < 2; it++) {
            const int c = (t >> 6) + it * 4;       // 0..7
            const int kd = c >> 1, msp = c & 1;
            half8 ok, ov;
#pragma unroll
            for (int j = 0; j < 4; j++) {
                ok[j]     = tile[msp * 32 + l16][kd * 16 + q * 4 + j];
                ok[4 + j] = tile[msp * 32 + 16 + l16][kd * 16 + q * 4 + j];
                ov[j]     = tile[kd * 16 + q * 4 + j][msp * 32 + l16];
                ov[4 + j] = tile[kd * 16 + q * 4 + j][msp * 32 + 16 + l16];
            }
            *(half8*)(kaB + ((lt * 8 + c) << 9) + l * 8) = ok;
            *(half8*)(vtB + ((lt * 8 + c) << 9) + l * 8) = ov;
        }
    } else {
        // ---- prep_w: elementwise cvt ----
        const int i = (bi - 1280) * 256 + t;
        const size_t base = (size_t)i * 8;
        half8 h;
        if (isbf) {
            u16x8 u = *(const u16x8*)((const unsigned short*)win + base);
#pragma unroll
            for (int j = 0; j < 8; j++) h[j] = (_Float16)bf2f(u[j]);
        } else {
            const float* p = (const float*)win + base;
            f32x4 a0 = *(const f32x4*)(p);
            f32x4 a1 = *(const f32x4*)(p + 4);
#pragma unroll
            for (int j = 0; j < 4; j++) { h[j] = (_Float16)a0[j]; h[4 + j] = (_Float16)a1[j]; }
        }
        *(half8*)(w16 + base) = h;
    }
}

// ---------- fused layer: kv staged block-wide via global_load_lds ----------
// Grid (8 s-tiles of 128, NH, BB) = 512 blocks, 4 waves x 32 s. All 4 waves
// share the block's kv tiles: glds stages each tile ONCE per block (L2->LDS DMA,
// no VMEM return-path traffic -> 4x less than per-wave register loads, the
// R11/R13-identified shared-resource bound). Fragment order in LDS == glds
// lane*16B scatter; ds_read_b128 at lane*16B is conflict-free. Double-buffered
// groups of 2 tiles (64 KB LDS, 2 blocks/CU), 8 barriers total. Register P^T,
// ones-A MFMA row-sum, exp2 with log2e folded into q scale (all R11-proven).
__global__ __launch_bounds__(256, 2) void layer_fused(const _Float16* __restrict__ xg,
                                                      _Float16* __restrict__ xout,
                                                      const _Float16* __restrict__ w16,
                                                      const _Float16* __restrict__ kaF,
                                                      const _Float16* __restrict__ vtF,
                                                      const void* __restrict__ win,
                                                      void* __restrict__ outp,
                                                      int L) {
    __shared__ __align__(16) _Float16 kvbuf[2][2][8192];   // [buf][tile][16 chunks x 512]
    const int sb = blockIdx.x;
    const int h  = blockIdx.y;
    const int b  = blockIdx.z;
    const int t  = threadIdx.x;
    const int wv = t >> 6, lane = t & 63, l16 = lane & 15, quad = lane >> 4;
    const int s0 = sb * 128 + wv * 32;        // wave's 32 s-columns

    const _Float16* kaB = kaF + ((size_t)(L * NH + h) << 16);
    const _Float16* vtB = vtF + ((size_t)(L * NH + h) << 16);

    // stage group g (tiles 2g, 2g+1) into kvbuf[buf]: wave wv stages 4 of the
    // 16 chunks per tile. chunk c<8 = ka, c>=8 = vt.
    auto stage = [&](int g, int buf) {
#pragma unroll
        for (int ti = 0; ti < 2; ti++) {
            const int lt = g * 2 + ti;
#pragma unroll
            for (int j = 0; j < 4; j++) {
                const int c = wv * 4 + j;
                const _Float16* src = (c < 8)
                    ? kaB + (((lt * 8 + c) << 9))
                    : vtB + (((lt * 8 + (c - 8)) << 9));
                __builtin_amdgcn_global_load_lds(
                    (const __attribute__((address_space(1))) void*)(src + lane * 8),
                    (__attribute__((address_space(3))) void*)(&kvbuf[buf][ti][c * 512]),
                    16, 0, 0);
            }
        }
    };

    stage(0, 0);   // overlaps the gemm below

    // ---- gemm: q^T[d=64][s=32] for this head, registers only ----
    f32x4 gacc[4][2];
#pragma unroll
    for (int md = 0; md < 4; md++)
#pragma unroll
        for (int nt = 0; nt < 2; nt++)
#pragma unroll
            for (int r = 0; r < 4; r++) gacc[md][nt][r] = 0.0f;
    const _Float16* wb = w16 + ((size_t)L << 16) + ((size_t)(h * 64) << 8);
#pragma unroll
    for (int kk = 0; kk < 8; kk++) {
        half8 bx[2];
#pragma unroll
        for (int nt = 0; nt < 2; nt++)
            bx[nt] = *(const half8*)(xg + ((size_t)((b << 10) + s0 + nt * 16 + l16) << 8) +
                                     kk * 32 + quad * 8);
#pragma unroll
        for (int md = 0; md < 4; md++) {
            half8 aw = *(const half8*)(wb + ((size_t)(md * 16 + l16) << 8) + kk * 32 + quad * 8);
            gacc[md][0] = __builtin_amdgcn_mfma_f32_16x16x32_f16(aw, bx[0], gacc[md][0], 0, 0, 0);
            gacc[md][1] = __builtin_amdgcn_mfma_f32_16x16x32_f16(aw, bx[1], gacc[md][1], 0, 0, 0);
        }
    }
    // q scale: 1/sqrt(64) * log2(e)
    half4 qh[4][2];
#pragma unroll
    for (int md = 0; md < 4; md++)
#pragma unroll
        for (int nt = 0; nt < 2; nt++)
#pragma unroll
            for (int r = 0; r < 4; r++)
                qh[md][nt][r] = (_Float16)(gacc[md][nt][r] * 0.180336880111120f);

    half4 ones4;
#pragma unroll
    for (int r = 0; r < 4; r++) ones4[r] = (_Float16)1.0f;

    f32x4 oacc[4][2];
    f32x4 osum[2];
#pragma unroll
    for (int md = 0; md < 4; md++)
#pragma unroll
        for (int nt = 0; nt < 2; nt++)
#pragma unroll
            for (int r = 0; r < 4; r++) oacc[md][nt][r] = 0.0f;
#pragma unroll
    for (int nt = 0; nt < 2; nt++)
#pragma unroll
        for (int r = 0; r < 4; r++) osum[nt][r] = 0.0f;

    __syncthreads();   // group 0 staged (syncthreads drains glds)

#pragma unroll 1
    for (int g = 0; g < 8; g++) {
        const int buf = g & 1;
        if (g + 1 < 8) stage(g + 1, buf ^ 1);

#pragma unroll
        for (int ti = 0; ti < 2; ti++) {
            const _Float16* base = &kvbuf[buf][ti][0];
            // conflict-free ds_read_b128 fragment loads
            half8 kab[8], vab[8];
#pragma unroll
            for (int c = 0; c < 8; c++)
                kab[c] = *(const half8*)(base + c * 512 + lane * 8);
#pragma unroll
            for (int c = 0; c < 8; c++)
                vab[c] = *(const half8*)(base + (8 + c) * 512 + lane * 8);

            // S^T = K . q^T : M=l 4x16, N=s 2x16, K=d in 4 steps of 16
            f32x4 stt[4][2];
#pragma unroll
            for (int ms = 0; ms < 4; ms++)
#pragma unroll
                for (int nt = 0; nt < 2; nt++)
#pragma unroll
                    for (int r = 0; r < 4; r++) stt[ms][nt][r] = 0.0f;
#pragma unroll
            for (int kd = 0; kd < 4; kd++)
#pragma unroll
                for (int msp = 0; msp < 2; msp++) {
                    half8 kk8 = kab[kd * 2 + msp];
                    half4 lo = __builtin_shufflevector(kk8, kk8, 0, 1, 2, 3);
                    half4 hi = __builtin_shufflevector(kk8, kk8, 4, 5, 6, 7);
#pragma unroll
                    for (int nt = 0; nt < 2; nt++) {
                        stt[msp * 2][nt] = __builtin_amdgcn_mfma_f32_16x16x16f16(
                            lo, qh[kd][nt], stt[msp * 2][nt], 0, 0, 0);
                        stt[msp * 2 + 1][nt] = __builtin_amdgcn_mfma_f32_16x16x16f16(
                            hi, qh[kd][nt], stt[msp * 2 + 1][nt], 0, 0, 0);
                    }
                }

            // exp2 in-register -> P^T B-frags
            half4 pb[4][2];
#pragma unroll
            for (int ms = 0; ms < 4; ms++)
#pragma unroll
                for (int nt = 0; nt < 2; nt++) {
                    float e0 = __builtin_amdgcn_exp2f(stt[ms][nt][0]);
                    float e1 = __builtin_amdgcn_exp2f(stt[ms][nt][1]);
                    float e2 = __builtin_amdgcn_exp2f(stt[ms][nt][2]);
                    float e3 = __builtin_amdgcn_exp2f(stt[ms][nt][3]);
                    half2v p01 = __builtin_bit_cast(half2v, __builtin_amdgcn_cvt_pkrtz(e0, e1));
                    half2v p23 = __builtin_bit_cast(half2v, __builtin_amdgcn_cvt_pkrtz(e2, e3));
                    pb[ms][nt] = __builtin_shufflevector(p01, p23, 0, 1, 2, 3);
                }

            // O^T += V^T . P^T ; row-sum tile on the MFMA pipe
#pragma unroll
            for (int ks = 0; ks < 4; ks++) {
#pragma unroll
                for (int nt = 0; nt < 2; nt++)
                    osum[nt] = __builtin_amdgcn_mfma_f32_16x16x16f16(
                        ones4, pb[ks][nt], osum[nt], 0, 0, 0);
#pragma unroll
                for (int mdp = 0; mdp < 2; mdp++) {
                    half8 vv8 = vab[ks * 2 + mdp];
                    half4 lo = __builtin_shufflevector(vv8, vv8, 0, 1, 2, 3);
                    half4 hi = __builtin_shufflevector(vv8, vv8, 4, 5, 6, 7);
#pragma unroll
                    for (int nt = 0; nt < 2; nt++) {
                        oacc[mdp * 2][nt] = __builtin_amdgcn_mfma_f32_16x16x16f16(
                            lo, pb[ks][nt], oacc[mdp * 2][nt], 0, 0, 0);
                        oacc[mdp * 2 + 1][nt] = __builtin_amdgcn_mfma_f32_16x16x16f16(
                            hi, pb[ks][nt], oacc[mdp * 2 + 1][nt], 0, 0, 0);
                    }
                }
            }
        }
        __syncthreads();   // drains next-group glds; protects buf reuse
    }

    // ---- normalize + store (every row of osum tile == lsum[s]) ----
    float inv[2];
#pragma unroll
    for (int nt = 0; nt < 2; nt++) inv[nt] = 1.0f / osum[nt][0];

    if (L < NL - 1) {
#pragma unroll
        for (int md = 0; md < 4; md++)
#pragma unroll
            for (int nt = 0; nt < 2; nt++) {
                const int s = s0 + nt * 16 + l16;
                half4 hv;
#pragma unroll
                for (int r = 0; r < 4; r++) hv[r] = (_Float16)(oacc[md][nt][r] * inv[nt]);
                *(half4*)(xout + (((size_t)((b << 10) + s)) << 8) + (h << 6) + md * 16 + quad * 4) = hv;
            }
    } else if (detect_flag(win)) {
#pragma unroll
        for (int md = 0; md < 4; md++)
#pragma unroll
            for (int nt = 0; nt < 2; nt++) {
                const int s = s0 + nt * 16 + l16;
#pragma unroll
                for (int r = 0; r < 4; r++) {
                    const int c = (h << 6) + md * 16 + quad * 4 + r;
                    ((unsigned short*)outp)[(((size_t)(b * CD + c)) << 10) + s] =
                        f2bf(oacc[md][nt][r] * inv[nt]);
                }
            }
    } else {
#pragma unroll
        for (int md = 0; md < 4; md++)
#pragma unroll
            for (int nt = 0; nt < 2; nt++) {
                const int s = s0 + nt * 16 + l16;
#pragma unroll
                for (int r = 0; r < 4; r++) {
                    const int c = (h << 6) + md * 16 + quad * 4 + r;
                    ((float*)outp)[(((size_t)(b * CD + c)) << 10) + s] =
                        oacc[md][nt][r] * inv[nt];
                }
            }
    }
}

extern "C" void kernel_launch(void* const* d_in, const int* in_sizes, int n_in,
                              void* d_out, int out_size, void* d_ws, size_t ws_size,
                              hipStream_t stream) {
    const void* xin = d_in[0];
    // d_in[1] = length: used only for its shape (L=1024) — values irrelevant
    const void* win = d_in[2];
    const void* kvin = d_in[3];

    char* ws = (char*)d_ws;
    const size_t MB = 1u << 20;
    _Float16* xa  = (_Float16*)(ws);               // 8 MB  (B,S,C) f16
    _Float16* xb  = (_Float16*)(ws + 8 * MB);      // 8 MB  ping-pong
    _Float16* w16 = (_Float16*)(ws + 16 * MB);     // 0.5 MB
    _Float16* kaF = (_Float16*)(ws + 17 * MB);     // 2 MB  K fragment-order
    _Float16* vtF = (_Float16*)(ws + 19 * MB);     // 2 MB  V^T fragment-order

    prep_all<<<dim3(1024 + 256 + 128), 256, 0, stream>>>(xin, win, kvin, xa, w16, kaF, vtF);

    _Float16* cur = xa;
    _Float16* nxt = xb;
    for (int i = 0; i < NL; i++) {
        layer_fused<<<dim3(SQL / 128, NH, BB), 256, 0, stream>>>(cur, nxt, w16, kaF, vtF,
                                                                 win, d_out, i);
        _Float16* tmp = cur; cur = nxt; nxt = tmp;
    }
}

// Round 15
// 223.429 us; speedup vs baseline: 3.3263x; 1.0068x over previous
//
#include <hip/hip_runtime.h>

#define NL   4
#define NH   4
#define HD   64
#define CD   256
#define SQL  1024
#define BB   16

typedef _Float16 half8 __attribute__((ext_vector_type(8)));
typedef _Float16 half4 __attribute__((ext_vector_type(4)));
typedef _Float16 half2v __attribute__((ext_vector_type(2)));
typedef float    f32x4 __attribute__((ext_vector_type(4)));
typedef unsigned short u16x8 __attribute__((ext_vector_type(8)));

static __device__ __forceinline__ float bf2f(unsigned short u) {
    union { unsigned int i; float f; } v; v.i = ((unsigned int)u) << 16; return v.f;
}
static __device__ __forceinline__ unsigned short f2bf(float f) {
    union { float f; unsigned int i; } v; v.f = f;
    unsigned int u = v.i;
    return (unsigned short)((u + 0x7fffu + ((u >> 16) & 1u)) >> 16);
}

// inline dtype detect: 1 = inputs are packed bf16, 0 = f32. Uniform scalar loop.
static __device__ __forceinline__ int detect_flag(const void* win) {
    const unsigned int* w = (const unsigned int*)win;
    int cnt = 0;
#pragma unroll 1
    for (int i = 0; i < 64; i++) {
        unsigned int lo = w[i] & 0xFFFFu;
        int e = (int)((lo >> 7) & 0xFF);
        cnt += (e >= 96 && e <= 144) ? 1 : 0;
    }
    return cnt >= 48 ? 1 : 0;
}

// ---------- merged prep ----------
// x: (B,C,S)->(B,S,C) f16 row-major (gemm B-frags).
// kv: -> kaF / vtF in MFMA-A-FRAGMENT ORDER: per (layer*NH+h), per l-tile,
//     8 chunks of [64 lanes][8 halfs]; glds-compatible (uniform base + lane*16B).
// w: elementwise cvt.
__global__ __launch_bounds__(256) void prep_all(const void* __restrict__ xin,
                                                const void* __restrict__ win,
                                                const void* __restrict__ kvin,
                                                _Float16* __restrict__ x16,
                                                _Float16* __restrict__ w16,
                                                _Float16* __restrict__ kaF,
                                                _Float16* __restrict__ vtF) {
    __shared__ __align__(16) _Float16 tile[64][72];
    const int bi = blockIdx.x;
    const int t = threadIdx.x;
    const int isbf = detect_flag(win);

    if (bi < 1024) {
        // ---- prep_x: (B,C,S) -> (B,S,C) f16 ----
        const int st = bi & 15, ct = (bi >> 4) & 3, b = bi >> 6;
        const int r = t >> 2, seg = t & 3;
        const size_t base = ((size_t)(b * CD + ct * 64 + r)) * SQL + st * 64 + seg * 16;
        float v[16];
        if (isbf) {
            const unsigned short* src = (const unsigned short*)xin + base;
            u16x8 u0 = *(const u16x8*)(src);
            u16x8 u1 = *(const u16x8*)(src + 8);
#pragma unroll
            for (int j = 0; j < 8; j++) { v[j] = bf2f(u0[j]); v[8 + j] = bf2f(u1[j]); }
        } else {
            const float* src = (const float*)xin + base;
#pragma unroll
            for (int c = 0; c < 4; c++) {
                f32x4 a = *(const f32x4*)(src + c * 4);
#pragma unroll
                for (int j = 0; j < 4; j++) v[c * 4 + j] = a[j];
            }
        }
#pragma unroll
        for (int j = 0; j < 16; j++) tile[r][seg * 16 + j] = (_Float16)v[j];
        __syncthreads();
        half8 o0, o1;
#pragma unroll
        for (int j = 0; j < 8; j++) { o0[j] = tile[seg * 16 + j][r]; o1[j] = tile[seg * 16 + 8 + j][r]; }
        _Float16* dt = x16 + ((size_t)(b * SQL + st * 64 + r)) * CD + ct * 64 + seg * 16;
        *(half8*)(dt) = o0;
        *(half8*)(dt + 8) = o1;
    } else if (bi < 1280) {
        // ---- prep_kv -> fragment-ordered kaF / vtF ----
        const int j2 = bi - 1024;
        const int lt = j2 & 15, ih = j2 >> 4;
        const int r = t >> 2, seg = t & 3;
        const size_t base = ((size_t)(ih * SQL + lt * 64 + r)) * HD + seg * 16;
        float v[16];
        if (isbf) {
            const unsigned short* src = (const unsigned short*)kvin + base;
            u16x8 u0 = *(const u16x8*)(src);
            u16x8 u1 = *(const u16x8*)(src + 8);
#pragma unroll
            for (int j = 0; j < 8; j++) { v[j] = bf2f(u0[j]); v[8 + j] = bf2f(u1[j]); }
        } else {
            const float* src = (const float*)kvin + base;
#pragma unroll
            for (int c = 0; c < 4; c++) {
                f32x4 a = *(const f32x4*)(src + c * 4);
#pragma unroll
                for (int j = 0; j < 4; j++) v[c * 4 + j] = a[j];
            }
        }
#pragma unroll
        for (int j = 0; j < 16; j++) tile[r][seg * 16 + j] = (_Float16)v[j];
        __syncthreads();
        const int l = t & 63, l16 = l & 15, q = l >> 4;
        _Float16* kaB = kaF + ((size_t)ih << 16);
        _Float16* vtB = vtF + ((size_t)ih << 16);
#pragma unroll
        for (int it = 0; it < 2; it++) {
            const int c = (t >> 6) + it * 4;       // 0..7
            const int kd = c >> 1, msp = c & 1;
            half8 ok, ov;
#pragma unroll
            for (int j = 0; j < 4; j++) {
                ok[j]     = tile[msp * 32 + l16][kd * 16 + q * 4 + j];
                ok[4 + j] = tile[msp * 32 + 16 + l16][kd * 16 + q * 4 + j];
                ov[j]     = tile[kd * 16 + q * 4 + j][msp * 32 + l16];
                ov[4 + j] = tile[kd * 16 + q * 4 + j][msp * 32 + 16 + l16];
            }
            *(half8*)(kaB + ((lt * 8 + c) << 9) + l * 8) = ok;
            *(half8*)(vtB + ((lt * 8 + c) << 9) + l * 8) = ov;
        }
    } else {
        // ---- prep_w: elementwise cvt ----
        const int i = (bi - 1280) * 256 + t;
        const size_t base = (size_t)i * 8;
        half8 h;
        if (isbf) {
            u16x8 u = *(const u16x8*)((const unsigned short*)win + base);
#pragma unroll
            for (int j = 0; j < 8; j++) h[j] = (_Float16)bf2f(u[j]);
        } else {
            const float* p = (const float*)win + base;
            f32x4 a0 = *(const f32x4*)(p);
            f32x4 a1 = *(const f32x4*)(p + 4);
#pragma unroll
            for (int j = 0; j < 4; j++) { h[j] = (_Float16)a0[j]; h[4 + j] = (_Float16)a1[j]; }
        }
        *(half8*)(w16 + base) = h;
    }
}

// ---------- fused layer: kv staged block-wide via global_load_lds ----------
// Grid (8 s-tiles of 128, NH, BB) = 512 blocks, 4 waves x 32 s. All 4 waves
// share the block's kv tiles: glds stages each tile ONCE per block (L2->LDS DMA,
// no VMEM return-path traffic — the R11/R13-identified shared-resource bound).
// Fragment order in LDS == glds lane*16B scatter; ds_read_b128 at lane*16B is
// conflict-free. SINGLE-tile double buffer (2 x 16 KB = 32 KB LDS, down from
// 64 KB in R14) so >2 blocks/CU can co-reside — R14's Occupancy 16% left every
// barrier drain exposed; co-resident blocks fill those stalls. Register P^T,
// ones-A MFMA row-sum, exp2 with log2e folded into q scale (all proven).
__global__ __launch_bounds__(256, 2) void layer_fused(const _Float16* __restrict__ xg,
                                                      _Float16* __restrict__ xout,
                                                      const _Float16* __restrict__ w16,
                                                      const _Float16* __restrict__ kaF,
                                                      const _Float16* __restrict__ vtF,
                                                      const void* __restrict__ win,
                                                      void* __restrict__ outp,
                                                      int L) {
    __shared__ __align__(16) _Float16 kvbuf[2][8192];   // [buf][16 chunks x 512 halfs]
    const int sb = blockIdx.x;
    const int h  = blockIdx.y;
    const int b  = blockIdx.z;
    const int t  = threadIdx.x;
    const int wv = t >> 6, lane = t & 63, l16 = lane & 15, quad = lane >> 4;
    const int s0 = sb * 128 + wv * 32;        // wave's 32 s-columns

    const _Float16* kaB = kaF + ((size_t)(L * NH + h) << 16);
    const _Float16* vtB = vtF + ((size_t)(L * NH + h) << 16);

    // stage l-tile lt into kvbuf[buf]: wave wv stages 4 of 16 chunks.
    // chunk c<8 = ka chunk c, c>=8 = vt chunk c-8.
    auto stage = [&](int lt, int buf) {
#pragma unroll
        for (int j = 0; j < 4; j++) {
            const int c = wv * 4 + j;
            const _Float16* src = (c < 8)
                ? kaB + (((lt * 8 + c) << 9))
                : vtB + (((lt * 8 + (c - 8)) << 9));
            __builtin_amdgcn_global_load_lds(
                (const __attribute__((address_space(1))) void*)(src + lane * 8),
                (__attribute__((address_space(3))) void*)(&kvbuf[buf][c * 512]),
                16, 0, 0);
        }
    };

    stage(0, 0);   // overlaps the gemm below

    // ---- gemm: q^T[d=64][s=32] for this head, registers only ----
    f32x4 gacc[4][2];
#pragma unroll
    for (int md = 0; md < 4; md++)
#pragma unroll
        for (int nt = 0; nt < 2; nt++)
#pragma unroll
            for (int r = 0; r < 4; r++) gacc[md][nt][r] = 0.0f;
    const _Float16* wb = w16 + ((size_t)L << 16) + ((size_t)(h * 64) << 8);
#pragma unroll
    for (int kk = 0; kk < 8; kk++) {
        half8 bx[2];
#pragma unroll
        for (int nt = 0; nt < 2; nt++)
            bx[nt] = *(const half8*)(xg + ((size_t)((b << 10) + s0 + nt * 16 + l16) << 8) +
                                     kk * 32 + quad * 8);
#pragma unroll
        for (int md = 0; md < 4; md++) {
            half8 aw = *(const half8*)(wb + ((size_t)(md * 16 + l16) << 8) + kk * 32 + quad * 8);
            gacc[md][0] = __builtin_amdgcn_mfma_f32_16x16x32_f16(aw, bx[0], gacc[md][0], 0, 0, 0);
            gacc[md][1] = __builtin_amdgcn_mfma_f32_16x16x32_f16(aw, bx[1], gacc[md][1], 0, 0, 0);
        }
    }
    // q scale: 1/sqrt(64) * log2(e)
    half4 qh[4][2];
#pragma unroll
    for (int md = 0; md < 4; md++)
#pragma unroll
        for (int nt = 0; nt < 2; nt++)
#pragma unroll
            for (int r = 0; r < 4; r++)
                qh[md][nt][r] = (_Float16)(gacc[md][nt][r] * 0.180336880111120f);

    half4 ones4;
#pragma unroll
    for (int r = 0; r < 4; r++) ones4[r] = (_Float16)1.0f;

    f32x4 oacc[4][2];
    f32x4 osum[2];
#pragma unroll
    for (int md = 0; md < 4; md++)
#pragma unroll
        for (int nt = 0; nt < 2; nt++)
#pragma unroll
            for (int r = 0; r < 4; r++) oacc[md][nt][r] = 0.0f;
#pragma unroll
    for (int nt = 0; nt < 2; nt++)
#pragma unroll
        for (int r = 0; r < 4; r++) osum[nt][r] = 0.0f;

    __syncthreads();   // tile 0 staged (syncthreads drains glds)

#pragma unroll 1
    for (int lt = 0; lt < 16; lt++) {
        const int buf = lt & 1;
        if (lt + 1 < 16) stage(lt + 1, buf ^ 1);

        const _Float16* base = &kvbuf[buf][0];
        // conflict-free ds_read_b128 fragment loads
        half8 kab[8], vab[8];
#pragma unroll
        for (int c = 0; c < 8; c++)
            kab[c] = *(const half8*)(base + c * 512 + lane * 8);
#pragma unroll
        for (int c = 0; c < 8; c++)
            vab[c] = *(const half8*)(base + (8 + c) * 512 + lane * 8);

        // S^T = K . q^T : M=l 4x16, N=s 2x16, K=d in 4 steps of 16
        f32x4 stt[4][2];
#pragma unroll
        for (int ms = 0; ms < 4; ms++)
#pragma unroll
            for (int nt = 0; nt < 2; nt++)
#pragma unroll
                for (int r = 0; r < 4; r++) stt[ms][nt][r] = 0.0f;
#pragma unroll
        for (int kd = 0; kd < 4; kd++)
#pragma unroll
            for (int msp = 0; msp < 2; msp++) {
                half8 kk8 = kab[kd * 2 + msp];
                half4 lo = __builtin_shufflevector(kk8, kk8, 0, 1, 2, 3);
                half4 hi = __builtin_shufflevector(kk8, kk8, 4, 5, 6, 7);
#pragma unroll
                for (int nt = 0; nt < 2; nt++) {
                    stt[msp * 2][nt] = __builtin_amdgcn_mfma_f32_16x16x16f16(
                        lo, qh[kd][nt], stt[msp * 2][nt], 0, 0, 0);
                    stt[msp * 2 + 1][nt] = __builtin_amdgcn_mfma_f32_16x16x16f16(
                        hi, qh[kd][nt], stt[msp * 2 + 1][nt], 0, 0, 0);
                }
            }

        // exp2 in-register -> P^T B-frags
        half4 pb[4][2];
#pragma unroll
        for (int ms = 0; ms < 4; ms++)
#pragma unroll
            for (int nt = 0; nt < 2; nt++) {
                float e0 = __builtin_amdgcn_exp2f(stt[ms][nt][0]);
                float e1 = __builtin_amdgcn_exp2f(stt[ms][nt][1]);
                float e2 = __builtin_amdgcn_exp2f(stt[ms][nt][2]);
                float e3 = __builtin_amdgcn_exp2f(stt[ms][nt][3]);
                half2v p01 = __builtin_bit_cast(half2v, __builtin_amdgcn_cvt_pkrtz(e0, e1));
                half2v p23 = __builtin_bit_cast(half2v, __builtin_amdgcn_cvt_pkrtz(e2, e3));
                pb[ms][nt] = __builtin_shufflevector(p01, p23, 0, 1, 2, 3);
            }

        // O^T += V^T . P^T ; row-sum tile on the MFMA pipe
#pragma unroll
        for (int ks = 0; ks < 4; ks++) {
#pragma unroll
            for (int nt = 0; nt < 2; nt++)
                osum[nt] = __builtin_amdgcn_mfma_f32_16x16x16f16(
                    ones4, pb[ks][nt], osum[nt], 0, 0, 0);
#pragma unroll
            for (int mdp = 0; mdp < 2; mdp++) {
                half8 vv8 = vab[ks * 2 + mdp];
                half4 lo = __builtin_shufflevector(vv8, vv8, 0, 1, 2, 3);
                half4 hi = __builtin_shufflevector(vv8, vv8, 4, 5, 6, 7);
#pragma unroll
                for (int nt = 0; nt < 2; nt++) {
                    oacc[mdp * 2][nt] = __builtin_amdgcn_mfma_f32_16x16x16f16(
                        lo, pb[ks][nt], oacc[mdp * 2][nt], 0, 0, 0);
                    oacc[mdp * 2 + 1][nt] = __builtin_amdgcn_mfma_f32_16x16x16f16(
                        hi, pb[ks][nt], oacc[mdp * 2 + 1][nt], 0, 0, 0);
                }
            }
        }
        __syncthreads();   // drains next-tile glds; protects buf reuse
    }

    // ---- normalize + store (every row of osum tile == lsum[s]) ----
    float inv[2];
#pragma unroll
    for (int nt = 0; nt < 2; nt++) inv[nt] = 1.0f / osum[nt][0];

    if (L < NL - 1) {
#pragma unroll
        for (int md = 0; md < 4; md++)
#pragma unroll
            for (int nt = 0; nt < 2; nt++) {
                const int s = s0 + nt * 16 + l16;
                half4 hv;
#pragma unroll
                for (int r = 0; r < 4; r++) hv[r] = (_Float16)(oacc[md][nt][r] * inv[nt]);
                *(half4*)(xout + (((size_t)((b << 10) + s)) << 8) + (h << 6) + md * 16 + quad * 4) = hv;
            }
    } else if (detect_flag(win)) {
#pragma unroll
        for (int md = 0; md < 4; md++)
#pragma unroll
            for (int nt = 0; nt < 2; nt++) {
                const int s = s0 + nt * 16 + l16;
#pragma unroll
                for (int r = 0; r < 4; r++) {
                    const int c = (h << 6) + md * 16 + quad * 4 + r;
                    ((unsigned short*)outp)[(((size_t)(b * CD + c)) << 10) + s] =
                        f2bf(oacc[md][nt][r] * inv[nt]);
                }
            }
    } else {
#pragma unroll
        for (int md = 0; md < 4; md++)
#pragma unroll
            for (int nt = 0; nt < 2; nt++) {
                const int s = s0 + nt * 16 + l16;
#pragma unroll
                for (int r = 0; r < 4; r++) {
                    const int c = (h << 6) + md * 16 + quad * 4 + r;
                    ((float*)outp)[(((size_t)(b * CD + c)) << 10) + s] =
                        oacc[md][nt][r] * inv[nt];
                }
            }
    }
}

extern "C" void kernel_launch(void* const* d_in, const int* in_sizes, int n_in,
                              void* d_out, int out_size, void* d_ws, size_t ws_size,
                              hipStream_t stream) {
    const void* xin = d_in[0];
    // d_in[1] = length: used only for its shape (L=1024) — values irrelevant
    const void* win = d_in[2];
    const void* kvin = d_in[3];

    char* ws = (char*)d_ws;
    const size_t MB = 1u << 20;
    _Float16* xa  = (_Float16*)(ws);               // 8 MB  (B,S,C) f16
    _Float16* xb  = (_Float16*)(ws + 8 * MB);      // 8 MB  ping-pong
    _Float16* w16 = (_Float16*)(ws + 16 * MB);     // 0.5 MB
    _Float16* kaF = (_Float16*)(ws + 17 * MB);     // 2 MB  K fragment-order
    _Float16* vtF = (_Float16*)(ws + 19 * MB);     // 2 MB  V^T fragment-order

    prep_all<<<dim3(1024 + 256 + 128), 256, 0, stream>>>(xin, win, kvin, xa, w16, kaF, vtF);

    _Float16* cur = xa;
    _Float16* nxt = xb;
    for (int i = 0; i < NL; i++) {
        layer_fused<<<dim3(SQL / 128, NH, BB), 256, 0, stream>>>(cur, nxt, w16, kaF, vtF,
                                                                 win, d_out, i);
        _Float16* tmp = cur; cur = nxt; nxt = tmp;
    }
}